// Round 1
// baseline (188.448 us; speedup 1.0000x reference)
//
#include <hip/hip_runtime.h>
#include <math.h>

#define HIDDEN 64
#define SEQ 128
#define BATCH 64
#define NPTS (BATCH * SEQ)   // 8192
#define TMAXV 20.0f
#define L2E 1.4426950408889634f
#define LN2 0.6931471805599453f

__device__ __forceinline__ float fexp2(float x) { return __builtin_amdgcn_exp2f(x); }
__device__ __forceinline__ float flog2(float x) { return __builtin_amdgcn_logf(x); }
__device__ __forceinline__ float frcp(float x)  { return __builtin_amdgcn_rcpf(x); }
// sigmoid(x) = 1/(1+e^-x);  tanh(x) = 1 - 2/(e^{2x}+1)
__device__ __forceinline__ float fsigmoid(float x) { return frcp(1.0f + fexp2(-x * L2E)); }
__device__ __forceinline__ float ftanh(float x)    { return 1.0f - 2.0f * frcp(1.0f + fexp2(2.0f * x * L2E)); }

__device__ __forceinline__ float wave_sum(float v) {
    v += __shfl_xor(v, 1);
    v += __shfl_xor(v, 2);
    v += __shfl_xor(v, 4);
    v += __shfl_xor(v, 8);
    v += __shfl_xor(v, 16);
    v += __shfl_xor(v, 32);
    return v;
}

// Blocks [0,64): LSTM rollout, one batch per block, 256 threads (thread j = gate-row j).
// Blocks [64,192): expert-expert kernel-sum term (independent of the rollout) — uses
// the CUs the rollout leaves idle. 32 p-chunks x 4 q-splits of 2048.
__global__ __launch_bounds__(256) void gen_and_ee(
    const float* __restrict__ upool,   // [B,S]
    const float* __restrict__ texp,    // [B,S]
    const float* __restrict__ Wih,     // [256] (4H x 1)
    const float* __restrict__ Whh,     // [256,64]
    const float* __restrict__ bih,     // [256]
    const float* __restrict__ bhh,     // [256]
    const float* __restrict__ Vw,      // [64]
    const float* __restrict__ Vb,      // [1]
    float* __restrict__ tl,            // [NPTS] workspace (learner times, [B,S] flat)
    float* __restrict__ out)           // [1] loss accumulator
{
    __shared__ __align__(16) float hx_s[64];
    __shared__ float act_s[256];
    __shared__ float lu_s[SEQ];
    __shared__ float cum_s;
    __shared__ float2 qbuf[2048];

    const int bid = blockIdx.x;
    const int tid = threadIdx.x;

    if (bid < BATCH) {
        // ---------------- LSTM rollout for batch `bid` ----------------
        const int h = tid & 63;

        // W_hh row j in registers (64 VGPRs)
        float w[64];
        const float4* wrow = (const float4*)(Whh + tid * 64);
        #pragma unroll
        for (int k4 = 0; k4 < 16; ++k4) {
            float4 v = wrow[k4];
            w[4 * k4 + 0] = v.x; w[4 * k4 + 1] = v.y;
            w[4 * k4 + 2] = v.z; w[4 * k4 + 3] = v.w;
        }
        const float bias = bih[tid] + bhh[tid];
        const float wih  = Wih[tid];
        const float vw   = (tid < 64) ? Vw[tid] : 0.0f;
        const float vb   = Vb[0];

        // precompute -ln(u) for all steps
        if (tid < SEQ) lu_s[tid] = -flog2(upool[bid * SEQ + tid]) * LN2;
        if (tid < 64) hx_s[tid] = 0.0f;

        float cx = 0.0f, hx = 0.0f;
        __syncthreads();

        // step 0: hx = 0 -> sigma = elu(Vb)+1
        float x0 = vb;
        float sigma0 = (x0 > 0.0f) ? (x0 + 1.0f) : fexp2(x0 * L2E);
        float cum = lu_s[0] * frcp(sigma0);
        if (tid == 0) { cum_s = cum; tl[bid * SEQ + 0] = cum; }
        __syncthreads();

        // iterations s = 0..126: gates for step s (uses cum_s of step s, hx of s-1),
        // then cell update for step s and cum for step s+1.
        for (int s = 0; s < SEQ - 1; ++s) {
            // matvec: gate-row j dot hx  (hx broadcast from LDS as float4)
            float dot = 0.0f;
            const float4* h4 = (const float4*)hx_s;
            #pragma unroll
            for (int k4 = 0; k4 < 16; ++k4) {
                float4 hv = h4[k4];
                dot = fmaf(w[4 * k4 + 0], hv.x, dot);
                dot = fmaf(w[4 * k4 + 1], hv.y, dot);
                dot = fmaf(w[4 * k4 + 2], hv.z, dot);
                dot = fmaf(w[4 * k4 + 3], hv.w, dot);
            }
            float g = dot + bias + cum_s * wih;
            // gate 2 (g) -> tanh, gates i/f/o -> sigmoid; wave-uniform branch
            float a = ((tid >> 6) == 2) ? ftanh(g) : fsigmoid(g);
            act_s[tid] = a;
            __syncthreads();

            if (tid < 64) {  // wave 0: cell update + sigma/cum for next step
                float ig = act_s[h];
                float fg = act_s[64 + h];
                float gg = act_s[128 + h];
                float og = act_s[192 + h];
                cx = fg * cx + ig * gg;
                hx = og * ftanh(cx);
                hx_s[h] = hx;
                float v = wave_sum(hx * vw);
                float xx = v + vb;
                float sig = (xx > 0.0f) ? (xx + 1.0f) : fexp2(xx * L2E);
                cum += lu_s[s + 1] * frcp(sig);
                if (tid == 0) { cum_s = cum; tl[bid * SEQ + s + 1] = cum; }
            }
            __syncthreads();
        }
    } else {
        // ---------------- expert-expert MMD term ----------------
        const int eb = bid - BATCH;      // 0..127
        const int pc = eb & 31;          // p-chunk 0..31 (256 points each)
        const int qs = eb >> 5;          // q-split 0..3 (2048 points each)

        const int p = pc * 256 + tid;
        const float tp = texp[p];
        const float mp = (tp < TMAXV && tp > 0.0f) ? 1.0f : 0.0f;

        const int q0 = qs * 2048;
        for (int i = tid; i < 2048; i += 256) {
            float tq = texp[q0 + i];
            float mq = (tq < TMAXV && tq > 0.0f) ? 1.0f : 0.0f;
            qbuf[i] = make_float2(tq, mq);
        }
        __syncthreads();

        float acc = 0.0f;
        #pragma unroll 4
        for (int i = 0; i < 2048; ++i) {
            float2 qq = qbuf[i];
            float d = tp - qq.x;
            acc = fmaf(qq.y, fexp2(d * d * (-L2E)), acc);
        }
        acc *= mp;
        acc = wave_sum(acc);
        if ((tid & 63) == 0) atomicAdd(out, acc);
    }
}

// ll + le terms: needs learner times from phase 1.
// Grid (32, 16): 32 p-chunks of 256 learner points x 16 q-splits of 512.
__global__ __launch_bounds__(256) void ll_le(
    const float* __restrict__ texp,
    const float* __restrict__ tl,
    float* __restrict__ out)
{
    __shared__ __align__(16) float4 qbuf[512];
    __shared__ float red[4];

    const int pc = blockIdx.x;
    const int qs = blockIdx.y;
    const int tid = threadIdx.x;

    const int p = pc * 256 + tid;
    const float tlp = tl[p];
    const float mlp = (tlp < TMAXV && tlp > 0.0f) ? 1.0f : 0.0f;

    const int q0 = qs * 512;
    for (int i = tid; i < 512; i += 256) {
        float tq = tl[q0 + i];
        float mq = (tq < TMAXV && tq > 0.0f) ? 1.0f : 0.0f;
        float te = texp[q0 + i];
        float me = (te < TMAXV && te > 0.0f) ? 1.0f : 0.0f;
        qbuf[i] = make_float4(tq, mq, te, me);
    }
    __syncthreads();

    float a_ll = 0.0f, a_le = 0.0f;
    #pragma unroll 4
    for (int i = 0; i < 512; ++i) {
        float4 q = qbuf[i];
        float d1 = tlp - q.x;
        a_ll = fmaf(q.y, fexp2(d1 * d1 * (-L2E)), a_ll);
        float d2 = tlp - q.z;
        a_le = fmaf(q.w, fexp2(d2 * d2 * (-L2E)), a_le);
    }
    float val = mlp * (a_ll - 2.0f * a_le);

    val = wave_sum(val);
    if ((tid & 63) == 0) red[tid >> 6] = val;
    __syncthreads();
    if (tid == 0) atomicAdd(out, red[0] + red[1] + red[2] + red[3]);
}

extern "C" void kernel_launch(void* const* d_in, const int* in_sizes, int n_in,
                              void* d_out, int out_size, void* d_ws, size_t ws_size,
                              hipStream_t stream) {
    const float* upool = (const float*)d_in[0];
    const float* texp  = (const float*)d_in[1];
    const float* Wih   = (const float*)d_in[2];
    const float* Whh   = (const float*)d_in[3];
    const float* bih   = (const float*)d_in[4];
    const float* bhh   = (const float*)d_in[5];
    const float* Vw    = (const float*)d_in[6];
    const float* Vb    = (const float*)d_in[7];
    float* out = (float*)d_out;
    float* tl  = (float*)d_ws;   // 8192 floats = 32 KB

    hipMemsetAsync(out, 0, sizeof(float), stream);
    hipLaunchKernelGGL(gen_and_ee, dim3(BATCH + 128), dim3(256), 0, stream,
                       upool, texp, Wih, Whh, bih, bhh, Vw, Vb, tl, out);
    hipLaunchKernelGGL(ll_le, dim3(32, 16), dim3(256), 0, stream, texp, tl, out);
}

// Round 2
// 160.858 us; speedup vs baseline: 1.1715x; 1.1715x over previous
//
#include <hip/hip_runtime.h>
#include <math.h>

#define HIDDEN 64
#define SEQ 128
#define BATCH 64
#define NPTS (BATCH * SEQ)   // 8192
#define TMAXV 20.0f
#define L2E 1.4426950408889634f
#define LN2 0.6931471805599453f

typedef float v2f __attribute__((ext_vector_type(2)));

__device__ __forceinline__ float fexp2(float x) { return __builtin_amdgcn_exp2f(x); }
__device__ __forceinline__ float flog2(float x) { return __builtin_amdgcn_logf(x); }
__device__ __forceinline__ float frcp(float x)  { return __builtin_amdgcn_rcpf(x); }
__device__ __forceinline__ float fsigmoid(float x) { return frcp(1.0f + fexp2(-x * L2E)); }
__device__ __forceinline__ float ftanh(float x)    { return 1.0f - 2.0f * frcp(1.0f + fexp2(2.0f * x * L2E)); }

// ---- DPP wave64 sum: VALU-pipe cross-lane (no LDS round trips). Result uniform.
template <int CTRL>
__device__ __forceinline__ float dpp_mov(float x) {
    int r = __builtin_amdgcn_update_dpp(0, __float_as_int(x), CTRL, 0xf, 0xf, false);
    return __int_as_float(r);
}
__device__ __forceinline__ float wave_sum_dpp(float x) {
    x += dpp_mov<0x111>(x);   // row_shr:1
    x += dpp_mov<0x112>(x);   // row_shr:2
    x += dpp_mov<0x114>(x);   // row_shr:4
    x += dpp_mov<0x118>(x);   // row_shr:8  -> lane 16r+15 = row sum
    x += dpp_mov<0x142>(x);   // row_bcast:15
    x += dpp_mov<0x143>(x);   // row_bcast:31 -> lane 63 = total
    return __int_as_float(__builtin_amdgcn_readlane(__float_as_int(x), 63));
}

__device__ __forceinline__ float wave_sum_shfl(float v) {
    v += __shfl_xor(v, 1);  v += __shfl_xor(v, 2);  v += __shfl_xor(v, 4);
    v += __shfl_xor(v, 8);  v += __shfl_xor(v, 16); v += __shfl_xor(v, 32);
    return v;
}

// Blocks [0,64): LSTM rollout, one batch per block, 256 threads (thread j = gate-row j).
// Blocks [64,192): expert-expert MMD term (input-only) on the idle CUs.
__global__ __launch_bounds__(256) void gen_and_ee(
    const float* __restrict__ upool,   // [B,S]
    const float* __restrict__ texp,    // [B,S]
    const float* __restrict__ Wih,     // [256]
    const float* __restrict__ Whh,     // [256,64]
    const float* __restrict__ bih,     // [256]
    const float* __restrict__ bhh,     // [256]
    const float* __restrict__ Vw,      // [64]
    const float* __restrict__ Vb,      // [1]
    float* __restrict__ tl,            // [NPTS] workspace
    float* __restrict__ out)           // [1] loss accumulator
{
    __shared__ float lu_s[SEQ];
    __shared__ float act_s[2][256];                 // double-buffered gate activations
    __shared__ __align__(16) float hx_s[4][64];     // per-wave private hx replicas
    __shared__ float2 qbuf[2048];

    const int bid = blockIdx.x;
    const int tid = threadIdx.x;

    if (bid < BATCH) {
        const int h  = tid & 63;
        const int wv = tid >> 6;

        // W_hh row `tid` in registers as 32 float2 (feeds v_pk_fma_f32)
        v2f w2[32];
        const float4* wrow = (const float4*)(Whh + tid * 64);
        #pragma unroll
        for (int k = 0; k < 16; ++k) {
            float4 v = wrow[k];
            w2[2 * k]     = (v2f){v.x, v.y};
            w2[2 * k + 1] = (v2f){v.z, v.w};
        }
        const float bias = bih[tid] + bhh[tid];
        const float wih  = Wih[tid];
        const float vw   = Vw[h];      // all waves: redundant sigma reduction
        const float vb   = Vb[0];

        if (tid < SEQ) lu_s[tid] = -flog2(upool[bid * SEQ + tid]) * LN2;
        hx_s[wv][h] = 0.0f;            // every wave zeroes its own replica
        float cx = 0.0f;
        __syncthreads();

        // step 0: hx = 0 -> sigma = elu(Vb)+1 (uniform)
        float sg0 = (vb > 0.0f) ? (vb + 1.0f) : fexp2(vb * L2E);
        float cum = lu_s[0] * frcp(sg0);
        if (tid == 0) tl[bid * SEQ + 0] = cum;

        for (int s = 0; s < SEQ - 1; ++s) {
            // gate-row dot hx, from this wave's private replica (broadcast b128 reads)
            const float4* h4 = (const float4*)hx_s[wv];
            v2f a0 = {0.f, 0.f}, a1 = {0.f, 0.f}, a2 = {0.f, 0.f}, a3 = {0.f, 0.f};
            #pragma unroll
            for (int k = 0; k < 16; k += 2) {
                float4 va = h4[k];
                float4 vbq = h4[k + 1];
                a0 = a0 + w2[2 * k]     * (v2f){va.x, va.y};
                a1 = a1 + w2[2 * k + 1] * (v2f){va.z, va.w};
                a2 = a2 + w2[2 * k + 2] * (v2f){vbq.x, vbq.y};
                a3 = a3 + w2[2 * k + 3] * (v2f){vbq.z, vbq.w};
            }
            v2f aa = (a0 + a1) + (a2 + a3);
            float g = (aa.x + aa.y) + bias + cum * wih;
            float a = (wv == 2) ? ftanh(g) : fsigmoid(g);
            act_s[s & 1][tid] = a;
            __syncthreads();   // the ONLY barrier per step

            // redundant cell update in every wave (bit-identical across waves)
            float ig = act_s[s & 1][h];
            float fg = act_s[s & 1][64 + h];
            float gg = act_s[s & 1][128 + h];
            float og = act_s[s & 1][192 + h];
            cx = fg * cx + ig * gg;
            float hx = og * ftanh(cx);
            hx_s[wv][h] = hx;          // own replica; in-wave lgkmcnt ordering only

            float tot = wave_sum_dpp(hx * vw);
            float xx  = tot + vb;
            float sg  = (xx > 0.0f) ? (xx + 1.0f) : fexp2(xx * L2E);
            cum += lu_s[s + 1] * frcp(sg);
            if (tid == 0) tl[bid * SEQ + s + 1] = cum;
        }
    } else {
        // ---------------- expert-expert MMD term ----------------
        const int eb = bid - BATCH;      // 0..127
        const int pc = eb & 31;          // p-chunk (256 points)
        const int qs = eb >> 5;          // q-split (2048 points)

        const int p = pc * 256 + tid;
        const float tp = texp[p];
        const float mp = (tp < TMAXV && tp > 0.0f) ? 1.0f : 0.0f;

        const int q0 = qs * 2048;
        for (int i = tid; i < 2048; i += 256) {
            float tq = texp[q0 + i];
            float mq = (tq < TMAXV && tq > 0.0f) ? 1.0f : 0.0f;
            qbuf[i] = make_float2(tq, mq);
        }
        __syncthreads();

        float acc = 0.0f;
        #pragma unroll 4
        for (int i = 0; i < 2048; ++i) {
            float2 qq = qbuf[i];
            float d = tp - qq.x;
            acc = fmaf(qq.y, fexp2(d * d * (-L2E)), acc);
        }
        acc *= mp;
        acc = wave_sum_shfl(acc);
        if ((tid & 63) == 0) atomicAdd(out, acc);
    }
}

// ll + le terms. Grid (32, 16): 32 p-chunks of 256 x 16 q-splits of 512.
__global__ __launch_bounds__(256) void ll_le(
    const float* __restrict__ texp,
    const float* __restrict__ tl,
    float* __restrict__ out)
{
    __shared__ __align__(16) float4 qbuf[512];
    __shared__ float red[4];

    const int pc = blockIdx.x;
    const int qs = blockIdx.y;
    const int tid = threadIdx.x;

    const int p = pc * 256 + tid;
    const float tlp = tl[p];
    const float mlp = (tlp < TMAXV && tlp > 0.0f) ? 1.0f : 0.0f;

    const int q0 = qs * 512;
    for (int i = tid; i < 512; i += 256) {
        float tq = tl[q0 + i];
        float mq = (tq < TMAXV && tq > 0.0f) ? 1.0f : 0.0f;
        float te = texp[q0 + i];
        float me = (te < TMAXV && te > 0.0f) ? 1.0f : 0.0f;
        qbuf[i] = make_float4(tq, mq, te, me);
    }
    __syncthreads();

    float val = 0.0f;
    // learner times are cumsum of Exp(1) increments: most p-points exceed T_MAX;
    // fully-masked waves skip the whole q-loop (wave-uniform branch).
    if (__ballot(mlp != 0.0f) != 0ULL) {
        float a_ll = 0.0f, a_le = 0.0f;
        #pragma unroll 4
        for (int i = 0; i < 512; ++i) {
            float4 q = qbuf[i];
            float d1 = tlp - q.x;
            a_ll = fmaf(q.y, fexp2(d1 * d1 * (-L2E)), a_ll);
            float d2 = tlp - q.z;
            a_le = fmaf(q.w, fexp2(d2 * d2 * (-L2E)), a_le);
        }
        val = mlp * (a_ll - 2.0f * a_le);
    }

    val = wave_sum_shfl(val);
    if ((tid & 63) == 0) red[tid >> 6] = val;
    __syncthreads();
    if (tid == 0) atomicAdd(out, red[0] + red[1] + red[2] + red[3]);
}

extern "C" void kernel_launch(void* const* d_in, const int* in_sizes, int n_in,
                              void* d_out, int out_size, void* d_ws, size_t ws_size,
                              hipStream_t stream) {
    const float* upool = (const float*)d_in[0];
    const float* texp  = (const float*)d_in[1];
    const float* Wih   = (const float*)d_in[2];
    const float* Whh   = (const float*)d_in[3];
    const float* bih   = (const float*)d_in[4];
    const float* bhh   = (const float*)d_in[5];
    const float* Vw    = (const float*)d_in[6];
    const float* Vb    = (const float*)d_in[7];
    float* out = (float*)d_out;
    float* tl  = (float*)d_ws;   // 8192 floats = 32 KB

    hipMemsetAsync(out, 0, sizeof(float), stream);
    hipLaunchKernelGGL(gen_and_ee, dim3(BATCH + 128), dim3(256), 0, stream,
                       upool, texp, Wih, Whh, bih, bhh, Vw, Vb, tl, out);
    hipLaunchKernelGGL(ll_le, dim3(32, 16), dim3(256), 0, stream, texp, tl, out);
}